// Round 10
// baseline (21386.926 us; speedup 1.0000x reference)
//
#include <hip/hip_runtime.h>
#include <math.h>

#define Bsz 512
#define Tsz 512
#define Fin 32
#define Hd 64
#define CHUNK 32
#define NCH (Tsz / CHUNK)

typedef float v2f __attribute__((ext_vector_type(2)));

// v_rcp_f32-based activations (~1 ulp; identical to all passing rounds)
__device__ __forceinline__ float fsig(float x) {
    return __builtin_amdgcn_rcpf(1.0f + __expf(-x));
}
__device__ __forceinline__ float ftanh(float x) {
    return fmaf(2.0f, __builtin_amdgcn_rcpf(1.0f + __expf(-2.0f * x)), -1.0f);
}

// Pin float4 components into arch VGPRs (blocks AGPR parking; R3-proven).
#define PIN4(v4) \
    asm volatile("" : "+v"((v4).x), "+v"((v4).y), "+v"((v4).z), "+v"((v4).w))

// ============================================================================
// R10: BOTH layers fused in one block, layer1 pipelined 2 supersteps behind.
//   waves 0-3: layer-0 recurrence, gate q=wv   (R3 layout: 96 weight VGPRs)
//   waves 4-7: layer-1 recurrence, gate q=wv-4 (128 weight VGPRs; < 256 cap,
//              the R9 spill lesson)
// h1[t] passes through a 4-slot LDS ring: written by wave 0 post-barrier at
// superstep t, read by L1 waves pre-barrier at superstep t+2 (barrier t+1
// orders the handoff; distance 1 would race). h1 NEVER goes to HBM and no
// workspace is used. One barrier per superstep, 514 supersteps total —
// exploiting the measured fact (R1/R4/R5/R6/R7) that the per-step window is
// ~fixed: two layers now ride in one window instead of two.
// Gate exchange per layer: R3's parity-double-buffered stride-5 buffer.
// Per-wave private h copies (hc0/hc1): same-wave in-order DS write->read,
// no barrier needed (R3-proven).
// ============================================================================
__global__ __launch_bounds__(512, 1)
void lstm_fused(const float* __restrict__ x,
                const float4* __restrict__ Wih0_4,
                const float4* __restrict__ Whh0_4,
                const float* __restrict__ bih0,
                const float* __restrict__ bhh0,
                const float4* __restrict__ Wih1_4,
                const float4* __restrict__ Whh1_4,
                const float* __restrict__ bih1,
                const float* __restrict__ bhh1,
                const float* __restrict__ fcW,
                const float* __restrict__ fcb,
                float* __restrict__ out)
{
    __shared__ __align__(16) float xbuf[2][CHUNK * Fin]; // 8 KB x staging
    __shared__ __align__(16) float ring[4][Hd];          // 1 KB h1 pipeline
    __shared__ float glds0[2][Hd * 5];                   // L0 gates (stride 5)
    __shared__ float glds1[2][Hd * 5];                   // L1 gates
    __shared__ __align__(16) float hc0[4][Hd];           // per-wave h, L0
    __shared__ __align__(16) float hc1[4][Hd];           // per-wave h, L1

    const int tid  = threadIdx.x;
    const int lane = tid & 63;
    const int wv   = tid >> 6;                      // 0..7
    const int wvu  = __builtin_amdgcn_readfirstlane(wv);
    const int q    = wv & 3;                        // gate within layer
    const int row  = q * Hd + lane;                 // PyTorch gate row
    const int b    = blockIdx.x;

    float4 wih[16];
    float4 whh[16];
    float  bias;

    if (wvu < 4) {
#pragma unroll
        for (int j = 0; j < 8; ++j)  wih[j] = Wih0_4[row * 8 + j];
#pragma unroll
        for (int j = 0; j < 16; ++j) whh[j] = Whh0_4[row * 16 + j];
        bias = bih0[row] + bhh0[row];
        hc0[wv][lane] = 0.0f;
    } else {
#pragma unroll
        for (int j = 0; j < 16; ++j) wih[j] = Wih1_4[row * 16 + j];
#pragma unroll
        for (int j = 0; j < 16; ++j) whh[j] = Whh1_4[row * 16 + j];
        bias = bih1[row] + bhh1[row];
        hc1[wv - 4][lane] = 0.0f;
    }

    const float4* xsrc = (const float4*)(x + (size_t)b * Tsz * Fin);
    if (tid < 256) ((float4*)xbuf[0])[tid] = xsrc[tid]; // chunk 0

    float c = 0.0f, hcur = 0.0f;
    const bool tg = ((wvu & 3) == 2);  // tanh gate, wave-uniform
    __syncthreads();

#pragma unroll 1
    for (int s = 0; s < Tsz + 2; ++s) {
        // stage next x chunk (first use is 32 barriers later)
        if ((s & (CHUNK - 1)) == 0 && s <= (NCH - 2) * CHUNK && tid < 256) {
            const int ci = s >> 5;
            ((float4*)xbuf[(ci + 1) & 1])[tid] =
                xsrc[(ci + 1) * (CHUNK * Fin / 4) + tid];
        }
        if (wvu < 4) {
            if (s < Tsz) {
#pragma unroll
                for (int j = 0; j < 8; ++j)  PIN4(wih[j]);
#pragma unroll
                for (int j = 0; j < 16; ++j) PIN4(whh[j]);
                const float4* xr =
                    (const float4*)&xbuf[(s >> 5) & 1][(s & 31) * Fin];
                v2f a0 = {bias, 0.0f}, a1 = {0.0f, 0.0f};
#pragma unroll
                for (int k = 0; k < 8; ++k) {
                    float4 xv = xr[k];
                    v2f b0 = {xv.x, xv.y}, b1 = {xv.z, xv.w};
                    v2f w0 = {wih[k].x, wih[k].y}, w1 = {wih[k].z, wih[k].w};
                    a0 = __builtin_elementwise_fma(b0, w0, a0);
                    a1 = __builtin_elementwise_fma(b1, w1, a1);
                }
                const float4* hr = (const float4*)&hc0[wv][0];
#pragma unroll
                for (int k = 0; k < 16; ++k) {
                    float4 hv = hr[k];
                    v2f b0 = {hv.x, hv.y}, b1 = {hv.z, hv.w};
                    v2f w0 = {whh[k].x, whh[k].y}, w1 = {whh[k].z, whh[k].w};
                    a0 = __builtin_elementwise_fma(b0, w0, a0);
                    a1 = __builtin_elementwise_fma(b1, w1, a1);
                }
                float a = (a0.x + a0.y) + (a1.x + a1.y);
                glds0[s & 1][lane * 5 + q] = tg ? ftanh(a) : fsig(a);
            }
        } else {
            if (s >= 2) {
#pragma unroll
                for (int j = 0; j < 16; ++j) PIN4(wih[j]);
#pragma unroll
                for (int j = 0; j < 16; ++j) PIN4(whh[j]);
                const int t = s - 2;
                const float4* xr = (const float4*)&ring[t & 3][0];
                v2f a0 = {bias, 0.0f}, a1 = {0.0f, 0.0f};
#pragma unroll
                for (int k = 0; k < 16; ++k) {
                    float4 xv = xr[k];
                    v2f b0 = {xv.x, xv.y}, b1 = {xv.z, xv.w};
                    v2f w0 = {wih[k].x, wih[k].y}, w1 = {wih[k].z, wih[k].w};
                    a0 = __builtin_elementwise_fma(b0, w0, a0);
                    a1 = __builtin_elementwise_fma(b1, w1, a1);
                }
                const float4* hr = (const float4*)&hc1[wv - 4][0];
#pragma unroll
                for (int k = 0; k < 16; ++k) {
                    float4 hv = hr[k];
                    v2f b0 = {hv.x, hv.y}, b1 = {hv.z, hv.w};
                    v2f w0 = {whh[k].x, whh[k].y}, w1 = {whh[k].z, whh[k].w};
                    a0 = __builtin_elementwise_fma(b0, w0, a0);
                    a1 = __builtin_elementwise_fma(b1, w1, a1);
                }
                float a = (a0.x + a0.y) + (a1.x + a1.y);
                glds1[t & 1][lane * 5 + q] = tg ? ftanh(a) : fsig(a);
            }
        }
        __syncthreads();   // the single per-superstep barrier
        if (wvu < 4) {
            if (s < Tsz) {
                const float* g = &glds0[s & 1][lane * 5];
                float gi = g[0], gf = g[1], gg = g[2], go = g[3];
                c    = fmaf(gf, c, gi * gg);
                hcur = go * ftanh(c);
                hc0[wv][lane] = hcur;              // own-wave, in-order
                if (wvu == 0) ring[s & 3][lane] = hcur; // h1[s] -> pipeline
            }
        } else {
            if (s >= 2) {
                const int t = s - 2;
                const float* g = &glds1[t & 1][lane * 5];
                float gi = g[0], gf = g[1], gg = g[2], go = g[3];
                c    = fmaf(gf, c, gi * gg);
                hcur = go * ftanh(c);
                hc1[wv - 4][lane] = hcur;
            }
        }
    }

    // fused FC: L1 wave 4's hcur = h2[b, T-1, lane]
    if (wvu == 4) {
        float psum = hcur * fcW[lane];
#pragma unroll
        for (int off = 32; off > 0; off >>= 1)
            psum += __shfl_down(psum, off);
        if (lane == 0) out[b] = psum + fcb[0];
    }
}

extern "C" void kernel_launch(void* const* d_in, const int* in_sizes, int n_in,
                              void* d_out, int out_size, void* d_ws, size_t ws_size,
                              hipStream_t stream)
{
    const float* x    = (const float*)d_in[0];
    const float* Wih0 = (const float*)d_in[1];
    const float* Whh0 = (const float*)d_in[2];
    const float* bih0 = (const float*)d_in[3];
    const float* bhh0 = (const float*)d_in[4];
    const float* Wih1 = (const float*)d_in[5];
    const float* Whh1 = (const float*)d_in[6];
    const float* bih1 = (const float*)d_in[7];
    const float* bhh1 = (const float*)d_in[8];
    const float* fcW  = (const float*)d_in[9];
    const float* fcb  = (const float*)d_in[10];
    float* out = (float*)d_out;
    (void)d_ws; (void)ws_size;   // no workspace needed: h1 lives in LDS ring

    lstm_fused<<<dim3(Bsz), dim3(512), 0, stream>>>(
        x, (const float4*)Wih0, (const float4*)Whh0, bih0, bhh0,
        (const float4*)Wih1, (const float4*)Whh1, bih1, bhh1,
        fcW, fcb, out);
}

// Round 11
// 1011.415 us; speedup vs baseline: 21.1455x; 21.1455x over previous
//
#include <hip/hip_runtime.h>
#include <math.h>

#define Bsz 512
#define Tsz 512
#define Fin 32
#define Hd 64

typedef float v2f __attribute__((ext_vector_type(2)));

// v_rcp_f32-based activations (no IEEE div sequence; ~1 ulp)
__device__ __forceinline__ float fsig(float x) {
    return __builtin_amdgcn_rcpf(1.0f + __expf(-x));
}
__device__ __forceinline__ float ftanh(float x) {
    return fmaf(2.0f, __builtin_amdgcn_rcpf(1.0f + __expf(-2.0f * x)), -1.0f);
}

// Pin float4 components into arch VGPRs (blocks AGPR parking; round-3 proven).
#define PIN4(v4) \
    asm volatile("" : "+v"((v4).x), "+v"((v4).y), "+v"((v4).z), "+v"((v4).w))

// lgkm-only barrier: orders LDS (gate exchange) WITHOUT draining vmcnt.
// hipcc's __syncthreads emits s_waitcnt vmcnt(0) before s_barrier, which
// force-completes in-flight global prefetch loads and store-retires at EVERY
// step (512x/kernel) - the theorized fixed cost behind R1/R4/R6/R7 nulls.
// Correctness: glds/hcopy writes ordered by lgkmcnt(0); xv prefetch loads get
// compiler vmcnt waits at their use; hout stores are consumed only by the
// next kernel (kernel boundary flushes).
#define BAR_LGKM()                                          \
    do {                                                    \
        asm volatile("s_waitcnt lgkmcnt(0)" ::: "memory");  \
        __builtin_amdgcn_s_barrier();                       \
        asm volatile("" ::: "memory");                      \
    } while (0)

// ---------------- Layer 0: x[B,T,32] -> h1[B,T,64] ----------------
// R4 structure (global x reads, depth-2 register prefetch, x-dot in the
// barrier shadow) with lgkm-only step barriers. One block (256 thr) per
// batch row; wave = gate; gates cross waves via parity-double-buffered
// stride-5 glds; per-wave private hcopy (own-wave in-order, no barrier).
__global__ __launch_bounds__(256, 2)
void lstm_layer0(const float* __restrict__ x,
                 const float4* __restrict__ Wih4,
                 const float4* __restrict__ Whh4,
                 const float* __restrict__ bih,
                 const float* __restrict__ bhh,
                 float* __restrict__ h1out)
{
    __shared__ __align__(16) float hcopy[4][Hd]; // per-wave private h
    __shared__ float glds[2][Hd * 5];            // gates, stride 5

    const int tid  = threadIdx.x;
    const int lane = tid & 63;
    const int wv   = tid >> 6;
    const int wvu  = __builtin_amdgcn_readfirstlane(wv);
    const int b    = blockIdx.x;

    float4 wih[8];
#pragma unroll
    for (int q = 0; q < 8; ++q) wih[q] = Wih4[tid * 8 + q];
    float4 whh[16];
#pragma unroll
    for (int q = 0; q < 16; ++q) whh[q] = Whh4[tid * 16 + q];
    const float bias = bih[tid] + bhh[tid];

    float c = 0.0f;
    hcopy[wv][lane] = 0.0f;

    const float4* xsrc = (const float4*)(x + (size_t)b * Tsz * Fin); // 8 f4/row
    float* hout = h1out + (size_t)b * Tsz * Hd + lane;

    // prologue: row0 -> ax, prefetch row1
    float4 xv[8];
#pragma unroll
    for (int q = 0; q < 8; ++q) xv[q] = xsrc[q];
    float ax;
    {
        v2f a0 = {bias, 0.0f}, a1 = {0.0f, 0.0f};
#pragma unroll
        for (int q = 0; q < 8; ++q) {
            float4 t4 = xv[q];
            v2f b0 = {t4.x, t4.y}, b1 = {t4.z, t4.w};
            v2f w0 = {wih[q].x, wih[q].y}, w1 = {wih[q].z, wih[q].w};
            a0 = __builtin_elementwise_fma(b0, w0, a0);
            a1 = __builtin_elementwise_fma(b1, w1, a1);
        }
        ax = (a0.x + a0.y) + (a1.x + a1.y);
    }
#pragma unroll
    for (int q = 0; q < 8; ++q) xv[q] = xsrc[8 + q];
    __syncthreads();

#pragma unroll 1
    for (int t = 0; t < Tsz; ++t) {
        const int p = t & 1;
#pragma unroll
        for (int q = 0; q < 8; ++q)  PIN4(wih[q]);
        // h-dot on top of prefetched ax
        const float4* hrow = (const float4*)&hcopy[wv][0];
        v2f a0 = {ax, 0.0f}, a1 = {0.0f, 0.0f};
#pragma unroll
        for (int q = 0; q < 16; ++q) {
            float4 hv = hrow[q];
            v2f b0 = {hv.x, hv.y}, b1 = {hv.z, hv.w};
            v2f w0 = {whh[q].x, whh[q].y}, w1 = {whh[q].z, whh[q].w};
            a0 = __builtin_elementwise_fma(b0, w0, a0);
            a1 = __builtin_elementwise_fma(b1, w1, a1);
        }
        float a = (a0.x + a0.y) + (a1.x + a1.y);
        if (wvu == 2) glds[p][lane * 5 + wv] = ftanh(a);
        else          glds[p][lane * 5 + wv] = fsig(a);

        // x-dot for t+1 from prefetched xv (loads issued last step)
        {
            v2f a0x = {bias, 0.0f}, a1x = {0.0f, 0.0f};
#pragma unroll
            for (int q = 0; q < 8; ++q) {
                float4 t4 = xv[q];
                v2f b0 = {t4.x, t4.y}, b1 = {t4.z, t4.w};
                v2f w0 = {wih[q].x, wih[q].y}, w1 = {wih[q].z, wih[q].w};
                a0x = __builtin_elementwise_fma(b0, w0, a0x);
                a1x = __builtin_elementwise_fma(b1, w1, a1x);
            }
            ax = (a0x.x + a0x.y) + (a1x.x + a1x.y);
        }
        // issue loads for row t+2 (consumed next step; survive the barrier)
        const int tn = (t + 2 < Tsz) ? (t + 2) : (Tsz - 1);
#pragma unroll
        for (int q = 0; q < 8; ++q) xv[q] = xsrc[(size_t)tn * 8 + q];

        BAR_LGKM();
        float gi = glds[p][lane * 5 + 0];
        float gf = glds[p][lane * 5 + 1];
        float gg = glds[p][lane * 5 + 2];
        float go = glds[p][lane * 5 + 3];
        c = fmaf(gf, c, gi * gg);
        float h = go * ftanh(c);
        hcopy[wv][lane] = h;
        if (wvu == 0) hout[(size_t)t * Hd] = h;  // fire-and-forget
    }
}

// ------- Layer 1 + FC: h1[B,T,64] -> out[B] -------
__global__ __launch_bounds__(256, 2)
void lstm_layer1_fc(const float* __restrict__ h1,
                    const float4* __restrict__ Wih4,
                    const float4* __restrict__ Whh4,
                    const float* __restrict__ bih,
                    const float* __restrict__ bhh,
                    const float* __restrict__ fcW,
                    const float* __restrict__ fcb,
                    float* __restrict__ out)
{
    __shared__ __align__(16) float hcopy[4][Hd];
    __shared__ float glds[2][Hd * 5];

    const int tid  = threadIdx.x;
    const int lane = tid & 63;
    const int wv   = tid >> 6;
    const int wvu  = __builtin_amdgcn_readfirstlane(wv);
    const int b    = blockIdx.x;

    float4 wih[16];
#pragma unroll
    for (int q = 0; q < 16; ++q) wih[q] = Wih4[tid * 16 + q];
    float4 whh[16];
#pragma unroll
    for (int q = 0; q < 16; ++q) whh[q] = Whh4[tid * 16 + q];
    const float bias = bih[tid] + bhh[tid];

    float c  = 0.0f;
    float hl = 0.0f;
    hcopy[wv][lane] = 0.0f;

    const float4* xsrc = (const float4*)(h1 + (size_t)b * Tsz * Hd); // 16 f4/row

    float4 xv[16];
#pragma unroll
    for (int q = 0; q < 16; ++q) xv[q] = xsrc[q];
    float ax;
    {
        v2f a0 = {bias, 0.0f}, a1 = {0.0f, 0.0f};
#pragma unroll
        for (int q = 0; q < 16; ++q) {
            float4 t4 = xv[q];
            v2f b0 = {t4.x, t4.y}, b1 = {t4.z, t4.w};
            v2f w0 = {wih[q].x, wih[q].y}, w1 = {wih[q].z, wih[q].w};
            a0 = __builtin_elementwise_fma(b0, w0, a0);
            a1 = __builtin_elementwise_fma(b1, w1, a1);
        }
        ax = (a0.x + a0.y) + (a1.x + a1.y);
    }
#pragma unroll
    for (int q = 0; q < 16; ++q) xv[q] = xsrc[16 + q];
    __syncthreads();

#pragma unroll 1
    for (int t = 0; t < Tsz; ++t) {
        const int p = t & 1;
#pragma unroll
        for (int q = 0; q < 16; ++q) PIN4(wih[q]);
        const float4* hrow = (const float4*)&hcopy[wv][0];
        v2f a0 = {ax, 0.0f}, a1 = {0.0f, 0.0f};
#pragma unroll
        for (int q = 0; q < 16; ++q) {
            float4 hv = hrow[q];
            v2f b0 = {hv.x, hv.y}, b1 = {hv.z, hv.w};
            v2f w0 = {whh[q].x, whh[q].y}, w1 = {whh[q].z, whh[q].w};
            a0 = __builtin_elementwise_fma(b0, w0, a0);
            a1 = __builtin_elementwise_fma(b1, w1, a1);
        }
        float a = (a0.x + a0.y) + (a1.x + a1.y);
        if (wvu == 2) glds[p][lane * 5 + wv] = ftanh(a);
        else          glds[p][lane * 5 + wv] = fsig(a);

        // x-dot for t+1 from prefetched xv
        {
            v2f a0x = {bias, 0.0f}, a1x = {0.0f, 0.0f};
#pragma unroll
            for (int q = 0; q < 16; ++q) {
                float4 t4 = xv[q];
                v2f b0 = {t4.x, t4.y}, b1 = {t4.z, t4.w};
                v2f w0 = {wih[q].x, wih[q].y}, w1 = {wih[q].z, wih[q].w};
                a0x = __builtin_elementwise_fma(b0, w0, a0x);
                a1x = __builtin_elementwise_fma(b1, w1, a1x);
            }
            ax = (a0x.x + a0x.y) + (a1x.x + a1x.y);
        }
        // issue loads for row t+2 (survive the barrier now)
        const int tn = (t + 2 < Tsz) ? (t + 2) : (Tsz - 1);
#pragma unroll
        for (int q = 0; q < 16; ++q) xv[q] = xsrc[(size_t)tn * 16 + q];

        BAR_LGKM();
        float gi = glds[p][lane * 5 + 0];
        float gf = glds[p][lane * 5 + 1];
        float gg = glds[p][lane * 5 + 2];
        float go = glds[p][lane * 5 + 3];
        c  = fmaf(gf, c, gi * gg);
        hl = go * ftanh(c);
        hcopy[wv][lane] = hl;
    }
    // fused FC on last h2 (wave 0 only; hl is replicated across waves)
    if (wvu == 0) {
        float psum = hl * fcW[lane];
#pragma unroll
        for (int off = 32; off > 0; off >>= 1)
            psum += __shfl_down(psum, off);
        if (lane == 0) out[b] = psum + fcb[0];
    }
}

extern "C" void kernel_launch(void* const* d_in, const int* in_sizes, int n_in,
                              void* d_out, int out_size, void* d_ws, size_t ws_size,
                              hipStream_t stream)
{
    const float* x    = (const float*)d_in[0];
    const float* Wih0 = (const float*)d_in[1];
    const float* Whh0 = (const float*)d_in[2];
    const float* bih0 = (const float*)d_in[3];
    const float* bhh0 = (const float*)d_in[4];
    const float* Wih1 = (const float*)d_in[5];
    const float* Whh1 = (const float*)d_in[6];
    const float* bih1 = (const float*)d_in[7];
    const float* bhh1 = (const float*)d_in[8];
    const float* fcW  = (const float*)d_in[9];
    const float* fcb  = (const float*)d_in[10];
    float* out = (float*)d_out;
    float* h1  = (float*)d_ws; // B*T*H fp32 = 64 MB scratch

    lstm_layer0<<<dim3(Bsz), dim3(256), 0, stream>>>(
        x, (const float4*)Wih0, (const float4*)Whh0, bih0, bhh0, h1);
    lstm_layer1_fc<<<dim3(Bsz), dim3(256), 0, stream>>>(
        h1, (const float4*)Wih1, (const float4*)Whh1, bih1, bhh1, fcW, fcb, out);
}